// Round 2
// baseline (537.626 us; speedup 1.0000x reference)
//
#include <hip/hip_runtime.h>

#define BB 16
#define SS 1024
#define HH 768
#define JJ 5

typedef __attribute__((ext_vector_type(4))) _Float16 h4_t;
typedef __attribute__((ext_vector_type(8))) _Float16 h8_t;
typedef __attribute__((ext_vector_type(4))) float f32x4;

#define WH_HALVES (JJ*HH*HH)            /* 2949120 */
#define WH_BYTES  (WH_HALVES*2)         /* 5898240 */
#define SC_FLOATS (BB*JJ*SS)            /* 81920   */
#define SC_BYTES  (SC_FLOATS*4)         /* 327680  */
#define FINAL_W   (JJ*2*HH + HH)        /* 8448    */
#define OUT2_OFF  (BB*FINAL_W)          /* 135168  */

// ---------------------------------------------------------------------------
// Kernel 0: convert W [5,768,768] f32 -> fp16, plus MFMA fragment-layout
// self-test (two candidate k-mappings for v_mfma_f32_16x16x32_f16).
// flag = 1 (two stacked 16x16x16 halves), 2 (contiguous 8-k per lane), 0 fail.
// ---------------------------------------------------------------------------
__global__ void k_convert_w(const float* __restrict__ W, _Float16* __restrict__ Wh,
                            int* __restrict__ flag)
{
    int i = blockIdx.x * 256 + threadIdx.x;
    if (i < WH_HALVES / 4) {
        float4 v = *(const float4*)(W + (size_t)i * 4);
        h4_t hv = { (_Float16)v.x, (_Float16)v.y, (_Float16)v.z, (_Float16)v.w };
        *(h4_t*)(Wh + (size_t)i * 4) = hv;
    }
    if (blockIdx.x == 0 && threadIdx.x < 64) {
        int l = threadIdx.x, l15 = l & 15, lg = l >> 4;
        h8_t a1, b1, a2, b2;
#pragma unroll
        for (int jj = 0; jj < 8; ++jj) {
            int k1 = (jj & 3) + 4 * lg + 16 * (jj >> 2);   // layout 1
            int k2 = jj + 8 * lg;                          // layout 2
            a1[jj] = (_Float16)(float)((l15 * 31 + k1 * 17) % 13 - 6);
            b1[jj] = (_Float16)(float)((k1 * 7 + l15 * 5) % 11 - 5);
            a2[jj] = (_Float16)(float)((l15 * 31 + k2 * 17) % 13 - 6);
            b2[jj] = (_Float16)(float)((k2 * 7 + l15 * 5) % 11 - 5);
        }
        f32x4 z = { 0.f, 0.f, 0.f, 0.f };
        f32x4 c1 = __builtin_amdgcn_mfma_f32_16x16x32_f16(a1, b1, z, 0, 0, 0);
        f32x4 c2 = __builtin_amdgcn_mfma_f32_16x16x32_f16(a2, b2, z, 0, 0, 0);
        int ok1 = 1, ok2 = 1;
#pragma unroll
        for (int r = 0; r < 4; ++r) {
            int row = lg * 4 + r;
            float ref = 0.f;
            for (int k = 0; k < 32; ++k)
                ref += (float)((row * 31 + k * 17) % 13 - 6) *
                       (float)((k * 7 + l15 * 5) % 11 - 5);
            ok1 &= (c1[r] == ref);
            ok2 &= (c2[r] == ref);
        }
        int all1 = __all(ok1);
        int all2 = __all(ok2);
        if (l == 0) flag[0] = all1 ? 1 : (all2 ? 2 : 0);
    }
}

// ---------------------------------------------------------------------------
// Kernel A v2: scores[b,j,s] = q_j . tanh(W_j h_s + b_j) for s in span.
// Block = (32-row tile, j, b); 4 waves; A-tile (32x768 fp16, 52 KB) resident
// in LDS -> 3 blocks/CU. Wave owns 192 cols; 2 passes of 96 cols (acc[2][6]).
// Register double-buffer of A (LDS) and B (global) fragments in the K loop.
// ---------------------------------------------------------------------------
#define LOADA(KS, AFR)                                                         \
    do {                                                                       \
        _Pragma("unroll")                                                      \
        for (int mf_ = 0; mf_ < 2; ++mf_) {                                    \
            int chunk_ = ((mf_ * 24 + (KS)) * 4 + lg) * 17 + l15;              \
            AFR[mf_] = *(const h8_t*)(Alds + chunk_ * 8);                      \
        }                                                                      \
    } while (0)

#define LOADB(KS, BFR)                                                         \
    do {                                                                       \
        _Pragma("unroll")                                                      \
        for (int nf_ = 0; nf_ < 6; ++nf_) {                                    \
            const _Float16* wp_ = wl + (size_t)(nbase + nf_ * 16) * HH + (KS) * 32; \
            if (LAYOUT == 2) {                                                 \
                BFR[nf_] = *(const h8_t*)(wp_ + lg * 8);                       \
            } else {                                                           \
                h4_t lo_ = *(const h4_t*)(wp_ + lg * 4);                       \
                h4_t hi_ = *(const h4_t*)(wp_ + 16 + lg * 4);                  \
                h8_t t_;                                                       \
                t_[0] = lo_[0]; t_[1] = lo_[1]; t_[2] = lo_[2]; t_[3] = lo_[3];\
                t_[4] = hi_[0]; t_[5] = hi_[1]; t_[6] = hi_[2]; t_[7] = hi_[3];\
                BFR[nf_] = t_;                                                 \
            }                                                                  \
        }                                                                      \
    } while (0)

#define MFMA6(AFR, BFR)                                                        \
    do {                                                                       \
        _Pragma("unroll")                                                      \
        for (int mf_ = 0; mf_ < 2; ++mf_)                                      \
            _Pragma("unroll")                                                  \
            for (int nf_ = 0; nf_ < 6; ++nf_)                                  \
                acc[mf_][nf_] = __builtin_amdgcn_mfma_f32_16x16x32_f16(        \
                    AFR[mf_], BFR[nf_], acc[mf_][nf_], 0, 0, 0);               \
    } while (0)

template<int LAYOUT>
__device__ __forceinline__ void scores_body(
    const float* __restrict__ hsrc,      // hidden + (b*SS+s0)*HH
    const _Float16* __restrict__ wbase,  // Wh + j*HH*HH
    const float* __restrict__ qv,        // attn_q + j*HH
    const float* __restrict__ bv,        // attn_b + j*HH
    _Float16* Alds, float* s_accw, int tid)
{
    // ---- stage A tile (32 x 768) f32 -> fp16 fragment-linear layout ----
#pragma unroll
    for (int i = 0; i < 24; ++i) {
        int f4 = i * 256 + tid;          // 0..6143
        int m  = f4 / 192;               // row 0..31
        int c4 = f4 - m * 192;
        int k  = c4 * 4;
        float4 v = *(const float4*)(hsrc + m * HH + k);
        int mf = m >> 4, mr = m & 15;
        int ks = k >> 5, kk = k & 31;    // kk in {0,4,...,28}
        int g, j0;
        if (LAYOUT == 2) { g = kk >> 3;        j0 = kk & 7; }
        else             { g = (kk & 15) >> 2; j0 = (kk >> 4) << 2; }
        int chunk = ((mf * 24 + ks) * 4 + g) * 17 + mr;  // 16B chunks, +1 pad
        h4_t hv = { (_Float16)v.x, (_Float16)v.y, (_Float16)v.z, (_Float16)v.w };
        *(h4_t*)(Alds + chunk * 8 + j0) = hv;
    }
    __syncthreads();

    const int wave = tid >> 6, lane = tid & 63;
    const int l15 = lane & 15, lg = lane >> 4;
    const _Float16* wl = wbase + (size_t)l15 * HH;

#pragma unroll
    for (int p = 0; p < 2; ++p) {
        const int nbase = wave * 192 + p * 96;
        f32x4 acc[2][6];
#pragma unroll
        for (int a = 0; a < 2; ++a)
#pragma unroll
            for (int c = 0; c < 6; ++c) acc[a][c] = (f32x4){0.f, 0.f, 0.f, 0.f};

        h8_t aA[2], bA[6], aB[2], bB[6];
        LOADA(0, aA); LOADB(0, bA);
        for (int ks = 0; ks < 24; ks += 2) {
            LOADA(ks + 1, aB); LOADB(ks + 1, bB);
            MFMA6(aA, bA);
            if (ks + 2 < 24) { LOADA(ks + 2, aA); LOADB(ks + 2, bA); }
            MFMA6(aB, bB);
        }

        // ---- epilogue: +bias, tanh, * q, reduce over this wave's 96 cols ---
        float qn[6], bn[6];
#pragma unroll
        for (int nf = 0; nf < 6; ++nf) {
            int n = nbase + nf * 16 + l15;
            qn[nf] = qv[n];
            bn[nf] = bv[n];
        }
#pragma unroll
        for (int mf = 0; mf < 2; ++mf) {
#pragma unroll
            for (int r = 0; r < 4; ++r) {
                float ssum = 0.f;
#pragma unroll
                for (int nf = 0; nf < 6; ++nf) {
                    float y = acc[mf][nf][r] + bn[nf];
                    y = fminf(fmaxf(y, -15.f), 15.f);
                    float e = __expf(2.f * y);
                    ssum += qn[nf] * ((e - 1.f) / (e + 1.f));
                }
#pragma unroll
                for (int off = 1; off < 16; off <<= 1)
                    ssum += __shfl_xor(ssum, off, 64);
                if (l15 == 0) s_accw[wave * 32 + mf * 16 + lg * 4 + r] += ssum;
            }
        }
    }
}

__global__ __launch_bounds__(256, 3) void k_scores(
    const float* __restrict__ hidden, const _Float16* __restrict__ Wh,
    const float* __restrict__ attn_b, const float* __restrict__ attn_q,
    const int* __restrict__ spans, float* __restrict__ scores,
    const int* __restrict__ flag)
{
    const int tile = blockIdx.x, j = blockIdx.y, b = blockIdx.z;
    const int s0 = tile * 32;
    const int start = spans[(b * JJ + j) * 2 + 0];
    const int end   = spans[(b * JJ + j) * 2 + 1];

    // Tiles with no span rows: nothing to do (pool kernel never reads them).
    if (s0 >= end || s0 + 32 <= start) return;

    __shared__ __align__(16) _Float16 Alds[3264 * 8];   // 52224 B
    __shared__ float s_accw[128];
    const int tid = threadIdx.x;
    if (tid < 128) s_accw[tid] = 0.f;

    const float* hsrc = hidden + ((size_t)(b * SS + s0)) * HH;
    const _Float16* wbase = Wh + (size_t)j * HH * HH;
    const float* qv = attn_q + j * HH;
    const float* bvp = attn_b + j * HH;

    int layout = flag[0];
    if (layout == 2) scores_body<2>(hsrc, wbase, qv, bvp, Alds, s_accw, tid);
    else             scores_body<1>(hsrc, wbase, qv, bvp, Alds, s_accw, tid);

    __syncthreads();
    if (tid < 32) {
        float v = s_accw[tid] + s_accw[32 + tid] + s_accw[64 + tid] + s_accw[96 + tid];
        scores[(b * JJ + j) * SS + s0 + tid] = v;
    }
}

// ---------------------------------------------------------------------------
// Kernel B: per (h-chunk, j, b): softmax over span + mean/att pooling,
// writes straight into final[b, j*1536 + {0,768} + h].
// ---------------------------------------------------------------------------
__global__ __launch_bounds__(256) void k_pool(
    const float* __restrict__ hidden, const float* __restrict__ scores,
    const int* __restrict__ spans, float* __restrict__ out)
{
    const int hc = blockIdx.x, j = blockIdx.y, b = blockIdx.z;
    const int tid = threadIdx.x;
    const int h = hc * 256 + tid;
    const int start = spans[(b * JJ + j) * 2 + 0];
    const int end   = spans[(b * JJ + j) * 2 + 1];
    const int count = end - start;
    float* fin = out + (size_t)b * FINAL_W + j * (2 * HH);

    if (count <= 0) {
        fin[h] = 0.f;
        fin[HH + h] = 0.f;
        return;
    }

    const float* sc = scores + (b * JJ + j) * SS;
    __shared__ float red[8];
    __shared__ float wbuf[SS];

    // max
    float lm = -3.0e38f;
    for (int s = start + tid; s < end; s += 256) lm = fmaxf(lm, sc[s]);
#pragma unroll
    for (int off = 32; off > 0; off >>= 1) lm = fmaxf(lm, __shfl_xor(lm, off, 64));
    int wid = tid >> 6, lane = tid & 63;
    if (lane == 0) red[wid] = lm;
    __syncthreads();
    float m = fmaxf(fmaxf(red[0], red[1]), fmaxf(red[2], red[3]));

    // denom
    float ld = 0.f;
    for (int s = start + tid; s < end; s += 256) ld += __expf(sc[s] - m);
#pragma unroll
    for (int off = 32; off > 0; off >>= 1) ld += __shfl_xor(ld, off, 64);
    if (lane == 0) red[4 + wid] = ld;
    __syncthreads();
    float inv_d = 1.f / (red[4] + red[5] + red[6] + red[7]);

    // weights to LDS
    for (int s = start + tid; s < end; s += 256)
        wbuf[s - start] = __expf(sc[s] - m) * inv_d;
    __syncthreads();

    float am = 0.f, aa = 0.f;
    const float* hp = hidden + ((size_t)b * SS) * HH + h;
    for (int i = 0; i < count; ++i) {
        float x = hp[(size_t)(start + i) * HH];
        am += x;
        aa += wbuf[i] * x;
    }
    fin[h] = am / (float)count;
    fin[HH + h] = aa;
}

// ---------------------------------------------------------------------------
// Tail: full_emb -> final[b, 7680:8448] and second output.
// ---------------------------------------------------------------------------
__global__ void k_tail(const float* __restrict__ full_emb, float* __restrict__ out)
{
    int i = blockIdx.x * 256 + threadIdx.x;   // 0..12287
    if (i >= BB * HH) return;
    int b = i / HH, h = i - b * HH;
    float v = full_emb[i];
    out[(size_t)b * FINAL_W + JJ * 2 * HH + h] = v;
    out[OUT2_OFF + i] = v;
}

// ---------------------------------------------------------------------------
extern "C" void kernel_launch(void* const* d_in, const int* in_sizes, int n_in,
                              void* d_out, int out_size, void* d_ws, size_t ws_size,
                              hipStream_t stream)
{
    const float* hidden   = (const float*)d_in[0];
    const float* full_emb = (const float*)d_in[1];
    const float* attn_W   = (const float*)d_in[2];
    const float* attn_b   = (const float*)d_in[3];
    const float* attn_q   = (const float*)d_in[4];
    const int*   spans    = (const int*)d_in[5];
    float* out = (float*)d_out;

    _Float16* Wh  = (_Float16*)d_ws;
    float* scores = (float*)((char*)d_ws + WH_BYTES);
    int*   flag   = (int*)((char*)d_ws + WH_BYTES + SC_BYTES);

    k_convert_w<<<(WH_HALVES / 4 + 255) / 256, 256, 0, stream>>>(attn_W, Wh, flag);
    k_scores<<<dim3(SS / 32, JJ, BB), 256, 0, stream>>>(hidden, Wh, attn_b, attn_q,
                                                        spans, scores, flag);
    k_pool<<<dim3(HH / 256, JJ, BB), 256, 0, stream>>>(hidden, scores, spans, out);
    k_tail<<<(BB * HH + 255) / 256, 256, 0, stream>>>(full_emb, out);
}

// Round 3
// 241.132 us; speedup vs baseline: 2.2296x; 2.2296x over previous
//
#include <hip/hip_runtime.h>

#define BB 16
#define SS 1024
#define HH 768
#define JJ 5
#define WHJ (HH*HH)
#define RIDX_J (BB*SS)                  /* 16384 rows max per head */

typedef __attribute__((ext_vector_type(4))) _Float16 h4_t;
typedef __attribute__((ext_vector_type(8))) _Float16 h8_t;
typedef __attribute__((ext_vector_type(4))) float f32x4;

#define WH_HALVES (JJ*HH*HH)            /* 2949120 */
#define WH_BYTES  (WH_HALVES*2)         /* 5898240 */
#define SC_FLOATS (BB*JJ*SS)            /* 81920   */
#define SC_BYTES  (SC_FLOATS*4)         /* 327680  */
#define RIDX_BYTES (JJ*RIDX_J*4)        /* 327680  */
#define FINAL_W   (JJ*2*HH + HH)        /* 8448    */
#define OUT2_OFF  (BB*FINAL_W)          /* 135168  */

// ---------------------------------------------------------------------------
// Kernel 0: W f32->fp16 convert + zero scores + MFMA layout self-test.
// meta[5] = layout flag (1: stacked 16x16x16 halves k=(j&3)+4lg+16(j>>2);
//                        2: contiguous k=j+8lg), 0 = fail.
// ---------------------------------------------------------------------------
__global__ void k_convert_w(const float* __restrict__ W, _Float16* __restrict__ Wh,
                            float* __restrict__ scores, int* __restrict__ meta)
{
    int i = blockIdx.x * 256 + threadIdx.x;
    if (i < WH_HALVES / 4) {
        float4 v = *(const float4*)(W + (size_t)i * 4);
        h4_t hv = { (_Float16)v.x, (_Float16)v.y, (_Float16)v.z, (_Float16)v.w };
        *(h4_t*)(Wh + (size_t)i * 4) = hv;
    }
    if (i < SC_FLOATS) scores[i] = 0.f;
    if (blockIdx.x == 0 && threadIdx.x < 64) {
        int l = threadIdx.x, l15 = l & 15, lg = l >> 4;
        h8_t a1, b1, a2, b2;
#pragma unroll
        for (int jj = 0; jj < 8; ++jj) {
            int k1 = (jj & 3) + 4 * lg + 16 * (jj >> 2);
            int k2 = jj + 8 * lg;
            a1[jj] = (_Float16)(float)((l15 * 31 + k1 * 17) % 13 - 6);
            b1[jj] = (_Float16)(float)((k1 * 7 + l15 * 5) % 11 - 5);
            a2[jj] = (_Float16)(float)((l15 * 31 + k2 * 17) % 13 - 6);
            b2[jj] = (_Float16)(float)((k2 * 7 + l15 * 5) % 11 - 5);
        }
        f32x4 z = { 0.f, 0.f, 0.f, 0.f };
        f32x4 c1 = __builtin_amdgcn_mfma_f32_16x16x32_f16(a1, b1, z, 0, 0, 0);
        f32x4 c2 = __builtin_amdgcn_mfma_f32_16x16x32_f16(a2, b2, z, 0, 0, 0);
        int ok1 = 1, ok2 = 1;
#pragma unroll
        for (int r = 0; r < 4; ++r) {
            int row = lg * 4 + r;
            float ref = 0.f;
            for (int k = 0; k < 32; ++k)
                ref += (float)((row * 31 + k * 17) % 13 - 6) *
                       (float)((k * 7 + l15 * 5) % 11 - 5);
            ok1 &= (c1[r] == ref);
            ok2 &= (c2[r] == ref);
        }
        int all1 = __all(ok1);
        int all2 = __all(ok2);
        if (l == 0) meta[5] = all1 ? 1 : (all2 ? 2 : 0);
    }
}

// ---------------------------------------------------------------------------
// Kernel 1: build gathered row index per head j: ridx[j][0..Mj) = b*S+s for
// every in-span (b,s). meta[j] = Mj.
// ---------------------------------------------------------------------------
__global__ void k_index(const int* __restrict__ spans, int* __restrict__ ridx,
                        int* __restrict__ meta)
{
    __shared__ int s_off[JJ * BB];
    int tid = threadIdx.x;
    if (tid == 0) {
        for (int j = 0; j < JJ; ++j) {
            int o = 0;
            for (int b = 0; b < BB; ++b) {
                int st = spans[(b * JJ + j) * 2 + 0];
                int en = spans[(b * JJ + j) * 2 + 1];
                s_off[j * BB + b] = o;
                o += (en > st) ? (en - st) : 0;
            }
            meta[j] = o;
        }
    }
    __syncthreads();
    for (int seg = 0; seg < JJ * BB; ++seg) {
        int j = seg / BB, b = seg % BB;
        int st = spans[(b * JJ + j) * 2 + 0];
        int en = spans[(b * JJ + j) * 2 + 1];
        int cnt = en - st;
        int base = j * RIDX_J + s_off[seg];
        for (int i = tid; i < cnt; i += 256)
            ridx[base + i] = b * SS + st + i;
    }
}

// ---------------------------------------------------------------------------
// Kernel 2: gathered dense GEMM per head. Block = (Mtile 128, Nblk of 128, j).
// C partial = q_n * tanh(h W^T + b) summed over block's 128 cols, atomicAdd
// into scores. LDS fragment-linear chunk layout (16B chunk per lane-frag,
// *17 pad) -> layout-agnostic b128 fragment reads.
// ---------------------------------------------------------------------------
template<int LAYOUT>
__device__ __forceinline__ void scores_body(
    const float* __restrict__ hidden, const _Float16* __restrict__ wj,
    const float* __restrict__ qv, const float* __restrict__ bvec,
    float* __restrict__ scores, const int* s_ridx,
    _Float16* Alds, _Float16* Blds, float* s_red,
    int j, int nblk, int valid_rows, int tid)
{
    const int m = tid >> 1, hh = tid & 1;           // staging row, k-half(32)
    const size_t arow = (size_t)s_ridx[m] * HH;
    const float*    ap = hidden + arow + hh * 32;
    const _Float16* bp = wj + (size_t)(nblk * 128 + m) * HH + hh * 32;
    const int mf = m >> 4, mr = m & 15;

    const int wave = tid >> 6, lane = tid & 63;
    const int l15 = lane & 15, lg = lane >> 4;
    const int wm = wave >> 1, wn = wave & 1;

    f32x4 acc[4][4];
#pragma unroll
    for (int a = 0; a < 4; ++a)
#pragma unroll
        for (int c = 0; c < 4; ++c) acc[a][c] = (f32x4){0.f, 0.f, 0.f, 0.f};

    for (int ks = 0; ks < 12; ++ks) {
        // issue global loads BEFORE the barrier: other waves' MFMA hides them
        float4 av[8];
        const float* a0 = ap + ks * 64;
#pragma unroll
        for (int i = 0; i < 8; ++i) av[i] = *(const float4*)(a0 + i * 4);
        h8_t bvv[4];
        const _Float16* b0 = bp + ks * 64;
#pragma unroll
        for (int i = 0; i < 4; ++i) bvv[i] = *(const h8_t*)(b0 + i * 8);

        __syncthreads();   // previous compute done -> LDS writable
#pragma unroll
        for (int i2 = 0; i2 < 4; ++i2) {
            float4 x = av[2 * i2], y = av[2 * i2 + 1];
            if (LAYOUT == 2) {
                int chunk = ((mf * 2 + hh) * 4 + i2) * 17 + mr;
                h8_t ha;
                ha[0] = (_Float16)x.x; ha[1] = (_Float16)x.y;
                ha[2] = (_Float16)x.z; ha[3] = (_Float16)x.w;
                ha[4] = (_Float16)y.x; ha[5] = (_Float16)y.y;
                ha[6] = (_Float16)y.z; ha[7] = (_Float16)y.w;
                *(h8_t*)(Alds + chunk * 8) = ha;
                *(h8_t*)(Blds + chunk * 8) = bvv[i2];
            } else {
                int g0 = (i2 & 1) * 2, j0 = (i2 >> 1) * 4;
                int c0 = ((mf * 2 + hh) * 4 + g0) * 17 + mr;
                h4_t alo = { (_Float16)x.x, (_Float16)x.y, (_Float16)x.z, (_Float16)x.w };
                h4_t ahi = { (_Float16)y.x, (_Float16)y.y, (_Float16)y.z, (_Float16)y.w };
                *(h4_t*)(Alds + c0 * 8 + j0)        = alo;
                *(h4_t*)(Alds + (c0 + 17) * 8 + j0) = ahi;
                h8_t bb = bvv[i2];
                h4_t blo = { bb[0], bb[1], bb[2], bb[3] };
                h4_t bhi = { bb[4], bb[5], bb[6], bb[7] };
                *(h4_t*)(Blds + c0 * 8 + j0)        = blo;
                *(h4_t*)(Blds + (c0 + 17) * 8 + j0) = bhi;
            }
        }
        __syncthreads();   // LDS ready
#pragma unroll
        for (int ks2 = 0; ks2 < 2; ++ks2) {
            h8_t af[4], bf[4];
#pragma unroll
            for (int f = 0; f < 4; ++f) {
                int ca = (((wm * 4 + f) * 2 + ks2) * 4 + lg) * 17 + l15;
                af[f] = *(const h8_t*)(Alds + ca * 8);
                int cb = (((wn * 4 + f) * 2 + ks2) * 4 + lg) * 17 + l15;
                bf[f] = *(const h8_t*)(Blds + cb * 8);
            }
#pragma unroll
            for (int a = 0; a < 4; ++a)
#pragma unroll
                for (int c = 0; c < 4; ++c)
                    acc[a][c] = __builtin_amdgcn_mfma_f32_16x16x32_f16(
                        af[a], bf[c], acc[a][c], 0, 0, 0);
        }
    }

    // ---- epilogue: +bias, tanh, *q, reduce over block's 128 cols ----------
    float qn[4], bn[4];
#pragma unroll
    for (int c = 0; c < 4; ++c) {
        int col = nblk * 128 + wn * 64 + c * 16 + l15;
        qn[c] = qv[col];
        bn[c] = bvec[col];
    }
#pragma unroll
    for (int a = 0; a < 4; ++a) {
#pragma unroll
        for (int r = 0; r < 4; ++r) {
            float ssum = 0.f;
#pragma unroll
            for (int c = 0; c < 4; ++c) {
                float yv = acc[a][c][r] + bn[c];
                yv = fminf(fmaxf(yv, -15.f), 15.f);
                float e = __expf(2.f * yv);
                ssum += qn[c] * ((e - 1.f) / (e + 1.f));
            }
#pragma unroll
            for (int off = 1; off < 16; off <<= 1)
                ssum += __shfl_xor(ssum, off, 64);
            if (l15 == 0)
                s_red[(wm * 2 + wn) * 64 + a * 16 + lg * 4 + r] = ssum;
        }
    }
    __syncthreads();
    if (tid < valid_rows) {
        int wm2 = tid >> 6, rl = tid & 63;
        float v = s_red[(wm2 * 2) * 64 + rl] + s_red[(wm2 * 2 + 1) * 64 + rl];
        int gidx = s_ridx[tid];
        atomicAdd(&scores[(gidx >> 10) * (JJ * SS) + j * SS + (gidx & 1023)], v);
    }
}

__global__ __launch_bounds__(256, 3) void k_scores(
    const float* __restrict__ hidden, const _Float16* __restrict__ Wh,
    const float* __restrict__ attn_b, const float* __restrict__ attn_q,
    float* __restrict__ scores, const int* __restrict__ ridx,
    const int* __restrict__ meta)
{
    const int tile = blockIdx.x, nblk = blockIdx.y, j = blockIdx.z;
    const int Mj = meta[j];
    const int rows_base = tile * 128;
    if (rows_base >= Mj) return;
    const int valid_rows = min(128, Mj - rows_base);

    __shared__ __align__(16) _Float16 Alds[1088 * 8];   // 17408 B
    __shared__ __align__(16) _Float16 Blds[1088 * 8];   // 17408 B
    __shared__ int   s_ridx[128];
    __shared__ float s_red[256];

    const int tid = threadIdx.x;
    if (tid < 128)
        s_ridx[tid] = ridx[j * RIDX_J + rows_base + min(tid, valid_rows - 1)];
    __syncthreads();

    const _Float16* wj = Wh + (size_t)j * WHJ;
    const float* qv = attn_q + j * HH;
    const float* bv = attn_b + j * HH;

    if (meta[5] == 2)
        scores_body<2>(hidden, wj, qv, bv, scores, s_ridx, Alds, Blds, s_red,
                       j, nblk, valid_rows, tid);
    else
        scores_body<1>(hidden, wj, qv, bv, scores, s_ridx, Alds, Blds, s_red,
                       j, nblk, valid_rows, tid);
}

// ---------------------------------------------------------------------------
// Kernel B: per (h-chunk, j, b): softmax over span + mean/att pooling.
// ---------------------------------------------------------------------------
__global__ __launch_bounds__(256) void k_pool(
    const float* __restrict__ hidden, const float* __restrict__ scores,
    const int* __restrict__ spans, float* __restrict__ out)
{
    const int hc = blockIdx.x, j = blockIdx.y, b = blockIdx.z;
    const int tid = threadIdx.x;
    const int h = hc * 256 + tid;
    const int start = spans[(b * JJ + j) * 2 + 0];
    const int end   = spans[(b * JJ + j) * 2 + 1];
    const int count = end - start;
    float* fin = out + (size_t)b * FINAL_W + j * (2 * HH);

    if (count <= 0) {
        fin[h] = 0.f;
        fin[HH + h] = 0.f;
        return;
    }

    const float* sc = scores + (b * JJ + j) * SS;
    __shared__ float red[8];
    __shared__ float wbuf[SS];

    float lm = -3.0e38f;
    for (int s = start + tid; s < end; s += 256) lm = fmaxf(lm, sc[s]);
#pragma unroll
    for (int off = 32; off > 0; off >>= 1) lm = fmaxf(lm, __shfl_xor(lm, off, 64));
    int wid = tid >> 6, lane = tid & 63;
    if (lane == 0) red[wid] = lm;
    __syncthreads();
    float m = fmaxf(fmaxf(red[0], red[1]), fmaxf(red[2], red[3]));

    float ld = 0.f;
    for (int s = start + tid; s < end; s += 256) ld += __expf(sc[s] - m);
#pragma unroll
    for (int off = 32; off > 0; off >>= 1) ld += __shfl_xor(ld, off, 64);
    if (lane == 0) red[4 + wid] = ld;
    __syncthreads();
    float inv_d = 1.f / (red[4] + red[5] + red[6] + red[7]);

    for (int s = start + tid; s < end; s += 256)
        wbuf[s - start] = __expf(sc[s] - m) * inv_d;
    __syncthreads();

    float am = 0.f, aa = 0.f;
    const float* hp = hidden + ((size_t)b * SS) * HH + h;
    for (int i = 0; i < count; ++i) {
        float x = hp[(size_t)(start + i) * HH];
        am += x;
        aa += wbuf[i] * x;
    }
    fin[h] = am / (float)count;
    fin[HH + h] = aa;
}

// ---------------------------------------------------------------------------
__global__ void k_tail(const float* __restrict__ full_emb, float* __restrict__ out)
{
    int i = blockIdx.x * 256 + threadIdx.x;
    if (i >= BB * HH) return;
    int b = i / HH, h = i - b * HH;
    float v = full_emb[i];
    out[(size_t)b * FINAL_W + JJ * 2 * HH + h] = v;
    out[OUT2_OFF + i] = v;
}

// ---------------------------------------------------------------------------
extern "C" void kernel_launch(void* const* d_in, const int* in_sizes, int n_in,
                              void* d_out, int out_size, void* d_ws, size_t ws_size,
                              hipStream_t stream)
{
    const float* hidden   = (const float*)d_in[0];
    const float* full_emb = (const float*)d_in[1];
    const float* attn_W   = (const float*)d_in[2];
    const float* attn_b   = (const float*)d_in[3];
    const float* attn_q   = (const float*)d_in[4];
    const int*   spans    = (const int*)d_in[5];
    float* out = (float*)d_out;

    _Float16* Wh  = (_Float16*)d_ws;
    float* scores = (float*)((char*)d_ws + WH_BYTES);
    int*   ridx   = (int*)((char*)d_ws + WH_BYTES + SC_BYTES);
    int*   meta   = (int*)((char*)d_ws + WH_BYTES + SC_BYTES + RIDX_BYTES);

    k_convert_w<<<(WH_HALVES / 4 + 255) / 256, 256, 0, stream>>>(attn_W, Wh, scores, meta);
    k_index<<<1, 256, 0, stream>>>(spans, ridx, meta);
    k_scores<<<dim3(RIDX_J / 128, HH / 128, JJ), 256, 0, stream>>>(
        hidden, Wh, attn_b, attn_q, scores, ridx, meta);
    k_pool<<<dim3(HH / 256, JJ, BB), 256, 0, stream>>>(hidden, scores, spans, out);
    k_tail<<<(BB * HH + 255) / 256, 256, 0, stream>>>(full_emb, out);
}

// Round 4
// 182.386 us; speedup vs baseline: 2.9477x; 1.3221x over previous
//
#include <hip/hip_runtime.h>

#define BB 16
#define SS 1024
#define HH 768
#define JJ 5
#define WHJ (HH*HH)
#define RIDX_J (BB*SS)                  /* 16384 rows max per head */
#define NSEG 4

typedef __attribute__((ext_vector_type(4))) _Float16 h4_t;
typedef __attribute__((ext_vector_type(8))) _Float16 h8_t;
typedef __attribute__((ext_vector_type(4))) float f32x4;

#define WH_HALVES (JJ*HH*HH)            /* 2949120  */
#define WH_BYTES  (WH_HALVES*2)         /* 5898240  */
#define HID_HALVES (BB*SS*HH)           /* 12582912 */
#define HID_BYTES (HID_HALVES*2)        /* 25165824 */
#define SC_FLOATS (BB*JJ*SS)            /* 81920    */
#define SC_BYTES  (SC_FLOATS*4)         /* 327680   */
#define RIDX_BYTES (JJ*RIDX_J*4)        /* 327680   */
#define FINAL_W   (JJ*2*HH + HH)        /* 8448     */
#define OUT2_OFF  (BB*FINAL_W)          /* 135168   */

// ---------------------------------------------------------------------------
// Kernel 0: convert W and hidden f32->fp16, zero scores + out span region,
// MFMA layout self-test. meta[5] = layout flag.
// ---------------------------------------------------------------------------
__global__ void k_convert(const float* __restrict__ W, const float* __restrict__ hidden,
                          _Float16* __restrict__ Wh, _Float16* __restrict__ Hh,
                          float* __restrict__ scores, float* __restrict__ out,
                          int* __restrict__ meta)
{
    int i = blockIdx.x * 256 + threadIdx.x;
    if (i < HID_HALVES / 4) {
        float4 v = *(const float4*)(hidden + (size_t)i * 4);
        h4_t hv = { (_Float16)v.x, (_Float16)v.y, (_Float16)v.z, (_Float16)v.w };
        *(h4_t*)(Hh + (size_t)i * 4) = hv;
    }
    if (i < WH_HALVES / 4) {
        float4 v = *(const float4*)(W + (size_t)i * 4);
        h4_t hv = { (_Float16)v.x, (_Float16)v.y, (_Float16)v.z, (_Float16)v.w };
        *(h4_t*)(Wh + (size_t)i * 4) = hv;
    }
    if (i < SC_FLOATS) scores[i] = 0.f;
    if (i < OUT2_OFF)  out[i] = 0.f;
    if (blockIdx.x == 0 && threadIdx.x < 64) {
        int l = threadIdx.x, l15 = l & 15, lg = l >> 4;
        h8_t a1, b1, a2, b2;
#pragma unroll
        for (int jj = 0; jj < 8; ++jj) {
            int k1 = (jj & 3) + 4 * lg + 16 * (jj >> 2);
            int k2 = jj + 8 * lg;
            a1[jj] = (_Float16)(float)((l15 * 31 + k1 * 17) % 13 - 6);
            b1[jj] = (_Float16)(float)((k1 * 7 + l15 * 5) % 11 - 5);
            a2[jj] = (_Float16)(float)((l15 * 31 + k2 * 17) % 13 - 6);
            b2[jj] = (_Float16)(float)((k2 * 7 + l15 * 5) % 11 - 5);
        }
        f32x4 z = { 0.f, 0.f, 0.f, 0.f };
        f32x4 c1 = __builtin_amdgcn_mfma_f32_16x16x32_f16(a1, b1, z, 0, 0, 0);
        f32x4 c2 = __builtin_amdgcn_mfma_f32_16x16x32_f16(a2, b2, z, 0, 0, 0);
        int ok1 = 1, ok2 = 1;
#pragma unroll
        for (int r = 0; r < 4; ++r) {
            int row = lg * 4 + r;
            float ref = 0.f;
            for (int k = 0; k < 32; ++k)
                ref += (float)((row * 31 + k * 17) % 13 - 6) *
                       (float)((k * 7 + l15 * 5) % 11 - 5);
            ok1 &= (c1[r] == ref);
            ok2 &= (c2[r] == ref);
        }
        int all1 = __all(ok1);
        int all2 = __all(ok2);
        if (l == 0) meta[5] = all1 ? 1 : (all2 ? 2 : 0);
    }
}

// ---------------------------------------------------------------------------
// Kernel 1: gathered row index per head j. meta[j] = Mj.
// ---------------------------------------------------------------------------
__global__ void k_index(const int* __restrict__ spans, int* __restrict__ ridx,
                        int* __restrict__ meta)
{
    __shared__ int s_off[JJ * BB];
    int tid = threadIdx.x;
    if (tid == 0) {
        for (int j = 0; j < JJ; ++j) {
            int o = 0;
            for (int b = 0; b < BB; ++b) {
                int st = spans[(b * JJ + j) * 2 + 0];
                int en = spans[(b * JJ + j) * 2 + 1];
                s_off[j * BB + b] = o;
                o += (en > st) ? (en - st) : 0;
            }
            meta[j] = o;
        }
    }
    __syncthreads();
    for (int seg = 0; seg < JJ * BB; ++seg) {
        int j = seg / BB, b = seg % BB;
        int st = spans[(b * JJ + j) * 2 + 0];
        int en = spans[(b * JJ + j) * 2 + 1];
        int cnt = en - st;
        int base = j * RIDX_J + s_off[seg];
        for (int i = tid; i < cnt; i += 256)
            ridx[base + i] = b * SS + st + i;
    }
}

// ---------------------------------------------------------------------------
// Kernel 2: gathered dense GEMM per head, fp16 A and B, pad-free chunk-linear
// LDS layout (conflict-free writes AND reads). BM=BN=128, BK=64, 4 waves,
// wave tile 64x64 (acc[4][4]). Partial col-sums atomicAdd'ed into scores.
// ---------------------------------------------------------------------------
template<int LAYOUT>
__device__ __forceinline__ void scores_body(
    const _Float16* __restrict__ Hh, const _Float16* __restrict__ wj,
    const float* __restrict__ qv, const float* __restrict__ bvec,
    float* __restrict__ scores, const int* s_ridx,
    _Float16* Alds, _Float16* Blds, float* s_red,
    int j, int nblk, int valid_rows, int tid)
{
    const int r  = tid >> 1, hh = tid & 1;       // staging row, k-half(32)
    const int mf = r >> 4,  mr = r & 15;
    const _Float16* ap = Hh + (size_t)s_ridx[r] * HH + hh * 32;
    const _Float16* bp = wj + (size_t)(nblk * 128 + r) * HH + hh * 32;

    const int wave = tid >> 6, lane = tid & 63;
    const int l15 = lane & 15, lg = lane >> 4;
    const int wm = wave >> 1, wn = wave & 1;

    f32x4 acc[4][4];
#pragma unroll
    for (int a = 0; a < 4; ++a)
#pragma unroll
        for (int c = 0; c < 4; ++c) acc[a][c] = (f32x4){0.f, 0.f, 0.f, 0.f};

    for (int ks = 0; ks < 12; ++ks) {
        h8_t av[4], bv4[4];
        const _Float16* a0 = ap + ks * 64;
        const _Float16* b0 = bp + ks * 64;
#pragma unroll
        for (int g2 = 0; g2 < 4; ++g2) {
            av[g2]  = *(const h8_t*)(a0 + g2 * 8);
            bv4[g2] = *(const h8_t*)(b0 + g2 * 8);
        }
        __syncthreads();   // prev iteration's reads done -> LDS writable
        if (LAYOUT == 2) {
#pragma unroll
            for (int g2 = 0; g2 < 4; ++g2) {
                int c = ((mf * 2 + hh) * 4 + g2) * 16 + mr;
                *(h8_t*)(Alds + c * 8) = av[g2];
                *(h8_t*)(Blds + c * 8) = bv4[g2];
            }
        } else {
#pragma unroll
            for (int g2 = 0; g2 < 4; ++g2) {
                int k0a = g2 * 8, k0b = g2 * 8 + 4;
                int ga = (k0a & 15) >> 2, ja = (k0a >> 4) << 2;
                int gb = (k0b & 15) >> 2, jb = (k0b >> 4) << 2;
                int cA = ((mf * 2 + hh) * 4 + ga) * 16 + mr;
                int cB = ((mf * 2 + hh) * 4 + gb) * 16 + mr;
                h8_t x = av[g2];
                h4_t alo = { x[0], x[1], x[2], x[3] };
                h4_t ahi = { x[4], x[5], x[6], x[7] };
                *(h4_t*)(Alds + cA * 8 + ja) = alo;
                *(h4_t*)(Alds + cB * 8 + jb) = ahi;
                h8_t y = bv4[g2];
                h4_t blo = { y[0], y[1], y[2], y[3] };
                h4_t bhi = { y[4], y[5], y[6], y[7] };
                *(h4_t*)(Blds + cA * 8 + ja) = blo;
                *(h4_t*)(Blds + cB * 8 + jb) = bhi;
            }
        }
        __syncthreads();   // LDS ready
#pragma unroll
        for (int ks2 = 0; ks2 < 2; ++ks2) {
            h8_t af[4], bf[4];
#pragma unroll
            for (int f = 0; f < 4; ++f) {
                int ca = (((wm * 4 + f) * 2 + ks2) * 4 + lg) * 16 + l15;
                af[f] = *(const h8_t*)(Alds + ca * 8);
                int cb = (((wn * 4 + f) * 2 + ks2) * 4 + lg) * 16 + l15;
                bf[f] = *(const h8_t*)(Blds + cb * 8);
            }
#pragma unroll
            for (int a = 0; a < 4; ++a)
#pragma unroll
                for (int c = 0; c < 4; ++c)
                    acc[a][c] = __builtin_amdgcn_mfma_f32_16x16x32_f16(
                        af[a], bf[c], acc[a][c], 0, 0, 0);
        }
    }

    // ---- epilogue: +bias, tanh, *q, reduce over block's 128 cols ----------
    float qn[4], bn[4];
#pragma unroll
    for (int c = 0; c < 4; ++c) {
        int col = nblk * 128 + wn * 64 + c * 16 + l15;
        qn[c] = qv[col];
        bn[c] = bvec[col];
    }
#pragma unroll
    for (int a = 0; a < 4; ++a) {
#pragma unroll
        for (int rr = 0; rr < 4; ++rr) {
            float ssum = 0.f;
#pragma unroll
            for (int c = 0; c < 4; ++c) {
                float yv = acc[a][c][rr] + bn[c];
                yv = fminf(fmaxf(yv, -15.f), 15.f);
                float e = __expf(2.f * yv);
                ssum += qn[c] * ((e - 1.f) / (e + 1.f));
            }
#pragma unroll
            for (int off = 1; off < 16; off <<= 1)
                ssum += __shfl_xor(ssum, off, 64);
            if (l15 == 0)
                s_red[(wm * 2 + wn) * 64 + a * 16 + lg * 4 + rr] = ssum;
        }
    }
    __syncthreads();
    if (tid < valid_rows) {
        int wm2 = tid >> 6, rl = tid & 63;
        float v = s_red[(wm2 * 2) * 64 + rl] + s_red[(wm2 * 2 + 1) * 64 + rl];
        int gidx = s_ridx[tid];
        atomicAdd(&scores[(gidx >> 10) * (JJ * SS) + j * SS + (gidx & 1023)], v);
    }
}

__global__ __launch_bounds__(256, 4) void k_scores(
    const _Float16* __restrict__ Hh, const _Float16* __restrict__ Wh,
    const float* __restrict__ attn_b, const float* __restrict__ attn_q,
    float* __restrict__ scores, const int* __restrict__ ridx,
    const int* __restrict__ meta)
{
    const int tile = blockIdx.x, nblk = blockIdx.y, j = blockIdx.z;
    const int Mj = meta[j];
    const int rows_base = tile * 128;
    if (rows_base >= Mj) return;
    const int valid_rows = min(128, Mj - rows_base);

    __shared__ __align__(16) _Float16 Alds[1024 * 8];   // 16384 B
    __shared__ __align__(16) _Float16 Blds[1024 * 8];   // 16384 B
    __shared__ int   s_ridx[128];
    __shared__ float s_red[256];

    const int tid = threadIdx.x;
    if (tid < 128)
        s_ridx[tid] = ridx[j * RIDX_J + rows_base + min(tid, valid_rows - 1)];
    __syncthreads();

    const _Float16* wj = Wh + (size_t)j * WHJ;
    const float* qv = attn_q + j * HH;
    const float* bv = attn_b + j * HH;

    if (meta[5] == 2)
        scores_body<2>(Hh, wj, qv, bv, scores, s_ridx, Alds, Blds, s_red,
                       j, nblk, valid_rows, tid);
    else
        scores_body<1>(Hh, wj, qv, bv, scores, s_ridx, Alds, Blds, s_red,
                       j, nblk, valid_rows, tid);
}

// ---------------------------------------------------------------------------
// Kernel 3: softmax over each span, normalize scores in place.
// ---------------------------------------------------------------------------
__global__ __launch_bounds__(256) void k_softmax(float* __restrict__ scores,
                                                 const int* __restrict__ spans)
{
    const int bj = blockIdx.x;                  // b*JJ + j
    const int start = spans[bj * 2 + 0];
    const int end   = spans[bj * 2 + 1];
    if (end <= start) return;
    float* sc = scores + bj * SS;
    const int tid = threadIdx.x;
    __shared__ float red[8];

    float lm = -3.0e38f;
    for (int s = start + tid; s < end; s += 256) lm = fmaxf(lm, sc[s]);
#pragma unroll
    for (int off = 32; off > 0; off >>= 1) lm = fmaxf(lm, __shfl_xor(lm, off, 64));
    int wid = tid >> 6, lane = tid & 63;
    if (lane == 0) red[wid] = lm;
    __syncthreads();
    float m = fmaxf(fmaxf(red[0], red[1]), fmaxf(red[2], red[3]));

    float ld = 0.f;
    for (int s = start + tid; s < end; s += 256) ld += __expf(sc[s] - m);
#pragma unroll
    for (int off = 32; off > 0; off >>= 1) ld += __shfl_xor(ld, off, 64);
    if (lane == 0) red[4 + wid] = ld;
    __syncthreads();
    float inv_d = 1.f / (red[4] + red[5] + red[6] + red[7]);

    for (int s = start + tid; s < end; s += 256)
        sc[s] = __expf(sc[s] - m) * inv_d;
}

// ---------------------------------------------------------------------------
// Kernel 4: segmented pooling: partial mean/att sums atomicAdd'ed into out.
// Grid (hc=3, iseg=NSEG, bj=80).
// ---------------------------------------------------------------------------
__global__ __launch_bounds__(256) void k_pool(
    const _Float16* __restrict__ Hh, const float* __restrict__ scores,
    const int* __restrict__ spans, float* __restrict__ out)
{
    const int hc = blockIdx.x, iseg = blockIdx.y, bj = blockIdx.z;
    const int b = bj / JJ, j = bj % JJ;
    const int start = spans[bj * 2 + 0];
    const int end   = spans[bj * 2 + 1];
    const int count = end - start;
    if (count <= 0) return;

    const int h = hc * 256 + threadIdx.x;
    const int i0 = start + (count * iseg) / NSEG;
    const int i1 = start + (count * (iseg + 1)) / NSEG;
    const float* w = scores + bj * SS;
    const _Float16* hp = Hh + (size_t)b * SS * HH + h;

    float am = 0.f, aa = 0.f;
    for (int s = i0; s < i1; ++s) {
        float x = (float)hp[(size_t)s * HH];
        am += x;
        aa += w[s] * x;
    }
    float* fin = out + (size_t)b * FINAL_W + j * (2 * HH);
    atomicAdd(&fin[h], am / (float)count);
    atomicAdd(&fin[HH + h], aa);
}

// ---------------------------------------------------------------------------
__global__ void k_tail(const float* __restrict__ full_emb, float* __restrict__ out)
{
    int i = blockIdx.x * 256 + threadIdx.x;
    if (i >= BB * HH) return;
    int b = i / HH, h = i - b * HH;
    float v = full_emb[i];
    out[(size_t)b * FINAL_W + JJ * 2 * HH + h] = v;
    out[OUT2_OFF + i] = v;
}

// ---------------------------------------------------------------------------
extern "C" void kernel_launch(void* const* d_in, const int* in_sizes, int n_in,
                              void* d_out, int out_size, void* d_ws, size_t ws_size,
                              hipStream_t stream)
{
    const float* hidden   = (const float*)d_in[0];
    const float* full_emb = (const float*)d_in[1];
    const float* attn_W   = (const float*)d_in[2];
    const float* attn_b   = (const float*)d_in[3];
    const float* attn_q   = (const float*)d_in[4];
    const int*   spans    = (const int*)d_in[5];
    float* out = (float*)d_out;

    char* ws = (char*)d_ws;
    _Float16* Wh  = (_Float16*)ws;
    _Float16* Hh  = (_Float16*)(ws + WH_BYTES);
    float* scores = (float*)(ws + WH_BYTES + HID_BYTES);
    int*   ridx   = (int*)(ws + WH_BYTES + HID_BYTES + SC_BYTES);
    int*   meta   = (int*)(ws + WH_BYTES + HID_BYTES + SC_BYTES + RIDX_BYTES);

    k_convert<<<HID_HALVES / 4 / 256, 256, 0, stream>>>(attn_W, hidden, Wh, Hh,
                                                        scores, out, meta);
    k_index<<<1, 256, 0, stream>>>(spans, ridx, meta);
    k_scores<<<dim3(RIDX_J / 128, HH / 128, JJ), 256, 0, stream>>>(
        Hh, Wh, attn_b, attn_q, scores, ridx, meta);
    k_softmax<<<BB * JJ, 256, 0, stream>>>(scores, spans);
    k_pool<<<dim3(HH / 256, NSEG, BB * JJ), 256, 0, stream>>>(Hh, scores, spans, out);
    k_tail<<<(BB * HH + 255) / 256, 256, 0, stream>>>(full_emb, out);
}